// Round 14
// baseline (1200.302 us; speedup 1.0000x reference)
//
#include <hip/hip_runtime.h>

#define N_ROWS 32768
#define DIM 256
#define N_CODES 8192
#define OUT_Q 8388608        // N_ROWS*DIM
#define OUT_LOSS 8388608
#define OUT_IDX 8388609
#define FLAG_GAP 7e-5f       // >= 2 grid cells (g=3.05e-5) + 2*split-err -> safe (8 runs proven)
#define GAP3 1e-4f           // rescan-needed threshold on s3 (wider, safety margin)
#define CAND_CAP 262144

// ws layout (bytes)
#define WS_AROW 0            // 32768 f32
#define WS_IDX  131072       // 32768 i32
#define WS_LIST 262144       // 32768 i32  (all flagged rows -> vq_apply)
#define WS_CNT  393216       // i32 flagcnt; +8 i32 cnt2; +16 i32 candcnt
#define WS_S1   393472       // 32768 f32
#define WS_KEYS 524544       // 32768 u64
#define WS_PART 524544       // aliased onto KEYS (keys dead before vq_out writes partials)
#define WS_EIMG 1048576      // 8MB E-image if ws allows, else d_out scratch

typedef __attribute__((ext_vector_type(8))) short short8x;
typedef __attribute__((ext_vector_type(4))) float f32x4;
typedef unsigned long long u64;

__device__ __forceinline__ u64 umin64(u64 a, u64 b) { return a < b ? a : b; }
// order-preserving float->uint map
__device__ __forceinline__ unsigned fkey(float f) {
    unsigned b = __float_as_uint(f);
    return b ^ (unsigned)(((int)b >> 31) | 0x80000000);
}
__device__ __forceinline__ float fkeyinv(unsigned u) {
    unsigned b = (u >> 31) ? (u ^ 0x80000000u) : ~u;
    return __uint_as_float(b);
}
__device__ __forceinline__ unsigned short bf16rne(float f) {
    unsigned u = __float_as_uint(f);
    return (unsigned short)((u + 0x7fff + ((u >> 16) & 1)) >> 16);
}
// merge two sorted u64 triples (a1<=a2<=a3), (b1<=b2<=b3) -> 3 smallest (in place in k1..k3)
__device__ __forceinline__ void triple_merge(u64& k1, u64& k2, u64& k3, u64 o1, u64 o2, u64 o3) {
    bool c = o1 < k1;
    u64 A1 = c ? o1 : k1, A2 = c ? o2 : k2, A3 = c ? o3 : k3;
    u64 B1 = c ? k1 : o1, B2 = c ? k2 : o2;
    bool d = B1 < A2;
    k1 = A1;
    k2 = d ? B1 : A2;
    k3 = d ? umin64(A2, B2) : umin64(A3, B1);
}

// ---------------- Kernel P: E -> bf16 h/l split, reg-load frag-linear image ----------------
// 256 chunks (tile 0..31 x S 0..7) of 32KB; chunk = 8 wave-blocks of 4KB.
// Fragment layout: off = ci*32768 + wv*4096 + c*1024 + lane*16 (h), +2048 (l)
//   lane holds code = tile*256 + wv*32 + c*16 + (lane&15), k = S*32 + (lane>>4)*8 + j
__global__ void vq_prepE(const float* __restrict__ E, char* __restrict__ Eimg) {
    int t = blockIdx.x * 256 + threadIdx.x;   // 0..262143
    int ci = t >> 10;
    int u = t & 1023;
    int wv = u >> 7;
    int v = u & 127;
    int c = v >> 6, lane = v & 63;
    int tile = ci >> 3, S = ci & 7;
    int code = tile * 256 + wv * 32 + c * 16 + (lane & 15);
    int k0 = S * 32 + (lane >> 4) * 8;
    const float* src = E + (size_t)code * DIM + k0;
    unsigned short h[8], l[8];
#pragma unroll
    for (int j = 0; j < 8; ++j) {
        float vv = src[j];
        h[j] = bf16rne(vv);
        float hf = __uint_as_float((unsigned)h[j] << 16);
        l[j] = bf16rne(vv - hf);
    }
    short8x H, L;
#pragma unroll
    for (int j = 0; j < 8; ++j) { H[j] = (short)h[j]; L[j] = (short)l[j]; }
    char* dst = Eimg + (size_t)ci * 32768 + wv * 4096 + c * 1024 + lane * 16;
    *(short8x*)dst = H;            // h plane
    *(short8x*)(dst + 2048) = L;   // l plane
}

// ---------------- Kernel A: per-row ||x||^2 in fp64 -> fp32 ----------------
__global__ void vq_rowA(const float* __restrict__ X, float* __restrict__ Arow) {
    int row = blockIdx.x * 4 + (threadIdx.x >> 6);
    int lane = threadIdx.x & 63;
    const float4 v = *((const float4*)(X + (size_t)row * DIM + lane * 4));
    double s = (double)v.x * v.x + (double)v.y * v.y + (double)v.z * v.z + (double)v.w * v.w;
#pragma unroll
    for (int m = 1; m < 64; m <<= 1) s += __shfl_xor(s, m, 64);
    if (lane == 0) Arow[row] = (float)s;
}

// ------- Kernel B: MFMA split-bf16 distance scan; E in REGISTERS, copy-free A/B
//   rotation, setprio around MFMA clusters, X in LDS. 2 blocks/CU (launch_bounds 4
//   waves/EU): 4 waves/SIMD give cross-block MFMA/VALU overlap.
//   MODE 0: all rows, TOP-3 argmin; flag rows (s2-s1<GAP); emit {i1,i2} candidates;
//           rows with s3-s1<=GAP3 go to rescan list2.
//   MODE 1: rescan rows from list2; task = (group, 2-tile range); emit cands <= s1+GAP.
template <int MODE>
__global__ __launch_bounds__(512, 4) void vq_scan(
    const float* __restrict__ X, const char* __restrict__ Eimg,
    const float* __restrict__ Arow, int* __restrict__ ws_idx,
    int* __restrict__ flaglist, int* __restrict__ flagcnt,
    u64* __restrict__ keybuf, float* __restrict__ s1buf,
    unsigned* __restrict__ cand, int* __restrict__ candcnt,
    int* __restrict__ list2, int* __restrict__ cnt2) {
    __shared__ alignas(16) unsigned short Xs[32768];   // 64KB: h plane, l plane
    __shared__ int rows_s[64];             // gathered row ids (MODE 1)

    const int tid = threadIdx.x;
    const int lane = tid & 63, wv = tid >> 6;      // wv 0..7
    const int l15 = lane & 15, sub = lane >> 4;

    const int cnt = (MODE == 1) ? *flagcnt : 0;
    const int ntasks = (MODE == 1) ? ((cnt + 63) >> 6) * 16 : 0;

    const char* const eimgw = Eimg + wv * 4096 + lane * 16;   // this wave+lane's E base

    float r1v[4][4], r2v[4][4], r3v[4][4];
    int c1v[4][4], c2v[4][4];
    if constexpr (MODE == 0) {
#pragma unroll
        for (int f = 0; f < 4; ++f)
#pragma unroll
            for (int g = 0; g < 4; ++g) {
                r1v[f][g] = 3.4e38f; r2v[f][g] = 3.4e38f; r3v[f][g] = 3.4e38f;
                c1v[f][g] = 0; c2v[f][g] = 0;
            }
    }

    int task = blockIdx.x;
    while (true) {
        int t0, t1, r0;
        if constexpr (MODE == 1) {
            if (task >= ntasks) break;
            int grp = task >> 4;
            int rng = task & 15;
            t0 = rng * 2; t1 = t0 + 2;
            r0 = 0;
            __syncthreads();   // all waves done with previous task's Xs/rows_s
            if (tid < 64) {
                int s = grp * 64 + tid;
                rows_s[tid] = flaglist[s < cnt ? s : cnt - 1];
            }
            __syncthreads();
        } else {
            t0 = 0; t1 = 32;
            r0 = blockIdx.x * 64;
        }
        const int cend = t1 * 8;

        // prologue: load first E chunk's fragments into register set A
        short8x cuA0, cuA1, cuA2, cuA3, cuB0, cuB1, cuB2, cuB3;
        {
            const char* p = eimgw + (size_t)(t0 * 8) * 32768;
            cuA0 = *(const short8x*)p;            // h, c=0
            cuA1 = *(const short8x*)(p + 1024);   // h, c=1
            cuA2 = *(const short8x*)(p + 2048);   // l, c=0
            cuA3 = *(const short8x*)(p + 3072);   // l, c=1
        }
        // stage X tile with in-register f32 -> bf16 h/l conversion
#pragma unroll
        for (int i = 0; i < 4; ++i) {
            int ci = tid + i * 512;                // 0..2047
            int q = ci >> 6, r = ci & 63;
            int grow = (MODE == 1) ? rows_s[r] : r0 + r;
            const float* src = X + (size_t)grow * DIM + q * 8;
            unsigned short h[8], l[8];
#pragma unroll
            for (int j = 0; j < 8; ++j) {
                float v = src[j];
                h[j] = bf16rne(v);
                float hf = __uint_as_float((unsigned)h[j] << 16);
                l[j] = bf16rne(v - hf);
            }
            short8x H, L;
#pragma unroll
            for (int j = 0; j < 8; ++j) { H[j] = (short)h[j]; L[j] = (short)l[j]; }
            *(short8x*)((char*)Xs + q * 1024 + r * 16) = H;
            *(short8x*)((char*)Xs + 32768 + q * 1024 + r * 16) = L;
        }

        float A_r[4][4], s1v[4][4];
        int rid[4][4];
#pragma unroll
        for (int f = 0; f < 4; ++f)
#pragma unroll
            for (int g = 0; g < 4; ++g) {
                int rr = (MODE == 1) ? rows_s[f * 16 + sub * 4 + g] : r0 + f * 16 + sub * 4 + g;
                A_r[f][g] = Arow[rr];
                if constexpr (MODE == 1) { s1v[f][g] = s1buf[rr]; rid[f][g] = rr; }
            }

        __syncthreads();   // X visible to all waves

#pragma unroll 1
        for (int t = t0; t < t1; ++t) {
            f32x4 acc[4][2];
#pragma unroll
            for (int f = 0; f < 4; ++f)
#pragma unroll
                for (int c = 0; c < 2; ++c) acc[f][c] = (f32x4){0.f, 0.f, 0.f, 0.f};

#pragma unroll 1
            for (int S = 0; S < 8; S += 2) {
                const char* xb = (const char*)Xs;
                // ---- even sub-step: consume cuA, prefetch directly into cuB ----
                {
                    const int ci = t * 8 + S;
                    const int cin = (ci + 1 < cend) ? ci + 1 : ci;
                    const char* p = eimgw + (size_t)cin * 32768;
                    cuB0 = *(const short8x*)p;
                    cuB1 = *(const short8x*)(p + 1024);
                    cuB2 = *(const short8x*)(p + 2048);
                    cuB3 = *(const short8x*)(p + 3072);

                    short8x ah[4], al[4];
#pragma unroll
                    for (int f = 0; f < 4; ++f) {
                        int off = (S * 4 + sub) * 1024 + f * 256 + l15 * 16;
                        ah[f] = *(const short8x*)(xb + off);
                        al[f] = *(const short8x*)(xb + 32768 + off);
                    }
                    __builtin_amdgcn_s_setprio(1);
#pragma unroll
                    for (int f = 0; f < 4; ++f) {
                        f32x4 a0 = acc[f][0];
                        a0 = __builtin_amdgcn_mfma_f32_16x16x32_bf16(al[f], cuA0, a0, 0, 0, 0);
                        a0 = __builtin_amdgcn_mfma_f32_16x16x32_bf16(ah[f], cuA2, a0, 0, 0, 0);
                        a0 = __builtin_amdgcn_mfma_f32_16x16x32_bf16(ah[f], cuA0, a0, 0, 0, 0);
                        acc[f][0] = a0;
                        f32x4 a1 = acc[f][1];
                        a1 = __builtin_amdgcn_mfma_f32_16x16x32_bf16(al[f], cuA1, a1, 0, 0, 0);
                        a1 = __builtin_amdgcn_mfma_f32_16x16x32_bf16(ah[f], cuA3, a1, 0, 0, 0);
                        a1 = __builtin_amdgcn_mfma_f32_16x16x32_bf16(ah[f], cuA1, a1, 0, 0, 0);
                        acc[f][1] = a1;
                    }
                    __builtin_amdgcn_s_setprio(0);
                }
                // ---- odd sub-step: consume cuB, prefetch directly into cuA ----
                {
                    const int ci = t * 8 + S + 1;
                    const int cin = (ci + 1 < cend) ? ci + 1 : ci;
                    const char* p = eimgw + (size_t)cin * 32768;
                    cuA0 = *(const short8x*)p;
                    cuA1 = *(const short8x*)(p + 1024);
                    cuA2 = *(const short8x*)(p + 2048);
                    cuA3 = *(const short8x*)(p + 3072);

                    short8x ah[4], al[4];
#pragma unroll
                    for (int f = 0; f < 4; ++f) {
                        int off = ((S + 1) * 4 + sub) * 1024 + f * 256 + l15 * 16;
                        ah[f] = *(const short8x*)(xb + off);
                        al[f] = *(const short8x*)(xb + 32768 + off);
                    }
                    __builtin_amdgcn_s_setprio(1);
#pragma unroll
                    for (int f = 0; f < 4; ++f) {
                        f32x4 a0 = acc[f][0];
                        a0 = __builtin_amdgcn_mfma_f32_16x16x32_bf16(al[f], cuB0, a0, 0, 0, 0);
                        a0 = __builtin_amdgcn_mfma_f32_16x16x32_bf16(ah[f], cuB2, a0, 0, 0, 0);
                        a0 = __builtin_amdgcn_mfma_f32_16x16x32_bf16(ah[f], cuB0, a0, 0, 0, 0);
                        acc[f][0] = a0;
                        f32x4 a1 = acc[f][1];
                        a1 = __builtin_amdgcn_mfma_f32_16x16x32_bf16(al[f], cuB1, a1, 0, 0, 0);
                        a1 = __builtin_amdgcn_mfma_f32_16x16x32_bf16(ah[f], cuB3, a1, 0, 0, 0);
                        a1 = __builtin_amdgcn_mfma_f32_16x16x32_bf16(ah[f], cuB1, a1, 0, 0, 0);
                        acc[f][1] = a1;
                    }
                    __builtin_amdgcn_s_setprio(0);
                }
            }

            const int cbase = t * 256 + wv * 32 + l15;   // + c*16
            if constexpr (MODE == 0) {
                // fold tile pair into running top-3 (values + idx for top-2)
#pragma unroll
                for (int f = 0; f < 4; ++f)
#pragma unroll
                    for (int g = 0; g < 4; ++g) {
                        float v0 = fmaf(-2.0f, acc[f][0][g], A_r[f][g]);
                        float v1 = fmaf(-2.0f, acc[f][1][g], A_r[f][g]);
                        bool sw = v1 < v0;
                        float lo = sw ? v1 : v0, hi = sw ? v0 : v1;
                        int ilo = sw ? cbase + 16 : cbase;
                        int ihi = sw ? cbase : cbase + 16;
                        bool cond = lo < r1v[f][g];
                        float A2 = cond ? hi : r2v[f][g];
                        float A3 = cond ? 3.4e38f : r3v[f][g];
                        float B1 = cond ? r1v[f][g] : lo;
                        float B2 = cond ? r2v[f][g] : hi;
                        int iA2 = cond ? ihi : c2v[f][g];
                        int iB1 = cond ? c1v[f][g] : ilo;
                        r1v[f][g] = cond ? lo : r1v[f][g];
                        c1v[f][g] = cond ? ilo : c1v[f][g];
                        bool d = B1 < A2;
                        r2v[f][g] = d ? B1 : A2;
                        c2v[f][g] = d ? iB1 : iA2;
                        r3v[f][g] = d ? fminf(A2, B2) : fminf(A3, B1);
                    }
            } else {
#pragma unroll
                for (int f = 0; f < 4; ++f)
#pragma unroll
                    for (int g = 0; g < 4; ++g) {
                        float thr = s1v[f][g] + FLAG_GAP;
#pragma unroll
                        for (int c = 0; c < 2; ++c) {
                            float v = fmaf(-2.0f, acc[f][c][g], A_r[f][g]);
                            if (v <= thr) {
                                int slot = atomicAdd(candcnt, 1);
                                if (slot < CAND_CAP)
                                    cand[slot] = ((unsigned)rid[f][g] << 13) |
                                                 (unsigned)(cbase + c * 16);
                            }
                        }
                    }
            }
        }

        if constexpr (MODE == 0) break;
        else task += gridDim.x;
    }

    if constexpr (MODE == 0) {
        __syncthreads();   // all waves done reading Xs before aliasing it as red[]
        u64* red = (u64*)Xs;   // [8 waves][64 rows][3] = 12KB
#pragma unroll
        for (int f = 0; f < 4; ++f)
#pragma unroll
            for (int g = 0; g < 4; ++g) {
                u64 k1 = ((u64)fkey(r1v[f][g]) << 32) | (unsigned)c1v[f][g];
                u64 k2 = ((u64)fkey(r2v[f][g]) << 32) | (unsigned)c2v[f][g];
                u64 k3 = ((u64)fkey(r3v[f][g]) << 32) | 0x1fffu;   // idx unused
#pragma unroll
                for (int m = 1; m < 16; m <<= 1) {
                    u64 o1 = __shfl_xor(k1, m, 64);
                    u64 o2 = __shfl_xor(k2, m, 64);
                    u64 o3 = __shfl_xor(k3, m, 64);
                    triple_merge(k1, k2, k3, o1, o2, o3);
                }
                if (l15 == 0) {
                    int row64 = f * 16 + sub * 4 + g;
                    red[(wv * 64 + row64) * 3 + 0] = k1;
                    red[(wv * 64 + row64) * 3 + 1] = k2;
                    red[(wv * 64 + row64) * 3 + 2] = k3;
                }
            }
        __syncthreads();
        if (tid < 64) {
            u64 K1 = red[tid * 3 + 0], K2 = red[tid * 3 + 1], K3 = red[tid * 3 + 2];
#pragma unroll
            for (int w = 1; w < 8; ++w) {
                triple_merge(K1, K2, K3,
                             red[(w * 64 + tid) * 3 + 0],
                             red[(w * 64 + tid) * 3 + 1],
                             red[(w * 64 + tid) * 3 + 2]);
            }
            int r = blockIdx.x * 64 + tid;
            ws_idx[r] = (int)(unsigned)(K1 & 0xffffffffull);
            float s1 = fkeyinv((unsigned)(K1 >> 32));
            float s2 = fkeyinv((unsigned)(K2 >> 32));
            float s3 = fkeyinv((unsigned)(K3 >> 32));
            s1buf[r] = s1;
            if (s2 - s1 < FLAG_GAP) {
                keybuf[r] = ~0ull;
                flaglist[atomicAdd(flagcnt, 1)] = r;
                int cs = atomicAdd(candcnt, 2);
                if (cs + 1 < CAND_CAP) {
                    cand[cs]     = ((unsigned)r << 13) | (unsigned)(K1 & 8191ull);
                    cand[cs + 1] = ((unsigned)r << 13) | (unsigned)(K2 & 8191ull);
                }
                if (s3 - s1 <= GAP3) list2[atomicAdd(cnt2, 1)] = r;
            }
        }
    }
}

// ------- Kernel C: fp64 np-semantics scoring of candidates, atomicMin merge -------
__global__ void vq_refine_cand(const float* __restrict__ X, const float* __restrict__ E,
                               const float* __restrict__ Arow, u64* __restrict__ keybuf,
                               const unsigned* __restrict__ cand,
                               const int* __restrict__ candcnt) {
    int cnt2 = *candcnt;
    cnt2 = cnt2 < CAND_CAP ? cnt2 : CAND_CAP;
    const int gw = (blockIdx.x * 256 + threadIdx.x) >> 6;   // global wave id
    const int nw = gridDim.x * 4;
    const int lane = threadIdx.x & 63;
    for (int i = gw; i < cnt2; i += nw) {
        unsigned p = cand[i];
        int row = (int)(p >> 13), code = (int)(p & 8191);
        float4 xv = *(const float4*)(X + (size_t)row * DIM + lane * 4);
        float4 ev = *(const float4*)(E + (size_t)code * DIM + lane * 4);
        double s = (double)xv.x * ev.x + (double)xv.y * ev.y +
                   (double)xv.z * ev.z + (double)xv.w * ev.w;
#pragma unroll
        for (int m = 1; m < 64; m <<= 1) s += __shfl_xor(s, m, 64);
        if (lane == 0) {
            float m32 = (float)s;
            float scr = fmaf(-2.0f, m32, Arow[row]);
            u64 key = ((u64)fkey(scr) << 32) | (unsigned)code;
            atomicMin(keybuf + row, key);
        }
    }
}

// ------- Kernel C2: apply refined winners (defensive: skip untouched sentinel) -------
__global__ void vq_apply(const u64* __restrict__ keybuf, const int* __restrict__ flaglist,
                         const int* __restrict__ flagcnt, int* __restrict__ ws_idx) {
    int s = blockIdx.x * 256 + threadIdx.x;
    if (s < *flagcnt) {
        int r = flaglist[s];
        u64 k = keybuf[r];
        if (k != ~0ull) ws_idx[r] = (int)(unsigned)(k & 0xffffffffull);
    }
}

// ---------------- Kernel D: gather quantized (ST-mimic), loss partials ----------------
__global__ void vq_out(const float* __restrict__ X, const float* __restrict__ E,
                       const int* __restrict__ ws_idx, float* __restrict__ out,
                       float* __restrict__ partials) {
    const int r = (blockIdx.x * 256 + threadIdx.x) >> 6;
    const int lane = threadIdx.x & 63;
    int idx = ws_idx[r];
    idx = idx < 0 ? 0 : (idx > N_CODES - 1 ? N_CODES - 1 : idx);   // defensive clamp
    float4 e = *((const float4*)(E + (size_t)idx * DIM + lane * 4));
    float4 x = *((const float4*)(X + (size_t)r * DIM + lane * 4));
    float dx = e.x - x.x, dy = e.y - x.y, dz = e.z - x.z, dw = e.w - x.w;
    float4 o;
    o.x = x.x + dx; o.y = x.y + dy; o.z = x.z + dz; o.w = x.w + dw;
    *((float4*)(out + (size_t)r * DIM + lane * 4)) = o;
    float s = dx * dx + dy * dy + dz * dz + dw * dw;
#pragma unroll
    for (int m = 1; m < 64; m <<= 1) s += __shfl_xor(s, m, 64);
    if (lane == 0) {
        partials[r] = s;
        out[OUT_IDX + r] = (float)idx;
    }
}

// ---------------- Kernel E: deterministic loss reduction ----------------
__global__ void vq_loss(const float* __restrict__ partials, float* __restrict__ out) {
    __shared__ double sred[4];
    double s = 0.0;
    for (int i = threadIdx.x; i < N_ROWS; i += 256) s += (double)partials[i];
#pragma unroll
    for (int m = 1; m < 64; m <<= 1) s += __shfl_xor(s, m, 64);
    if ((threadIdx.x & 63) == 0) sred[threadIdx.x >> 6] = s;
    __syncthreads();
    if (threadIdx.x == 0) {
        double t = sred[0] + sred[1] + sred[2] + sred[3];
        out[OUT_LOSS] = (float)(2.0 * t / (double)OUT_Q);
    }
}

extern "C" void kernel_launch(void* const* d_in, const int* in_sizes, int n_in,
                              void* d_out, int out_size, void* d_ws, size_t ws_size,
                              hipStream_t stream) {
    const float* X = (const float*)d_in[0];
    const float* E = (const float*)d_in[1];
    float* out = (float*)d_out;
    char* ws = (char*)d_ws;

    float* Arow = (float*)(ws + WS_AROW);
    int* idx = (int*)(ws + WS_IDX);
    int* list = (int*)(ws + WS_LIST);
    int* cnt = (int*)(ws + WS_CNT);
    int* cnt2 = (int*)(ws + WS_CNT + 8);
    int* ccnt = (int*)(ws + WS_CNT + 16);
    float* s1buf = (float*)(ws + WS_S1);
    u64* keys = (u64*)(ws + WS_KEYS);
    float* part = (float*)(ws + WS_PART);   // aliased onto keys (dead by then)
    char* eimg = (ws_size >= (size_t)(WS_EIMG + 8 * 1024 * 1024)) ? (ws + WS_EIMG) : (char*)d_out;
    unsigned* cand = (unsigned*)((char*)d_out + (16 << 20));   // [16MB,17MB) of d_out
    int* list2 = (int*)((char*)d_out + (17 << 20));            // [17MB,17.125MB) of d_out
    // both scratch regions are overwritten by vq_out afterwards

    hipMemsetAsync(ws + WS_CNT, 0, 32, stream);   // zero flagcnt + cnt2 + candcnt
    vq_prepE<<<1024, 256, 0, stream>>>(E, eimg);
    vq_rowA<<<N_ROWS / 4, 256, 0, stream>>>(X, Arow);
    vq_scan<0><<<N_ROWS / 64, 512, 0, stream>>>(X, eimg, Arow, idx, list, cnt, keys, s1buf,
                                                cand, ccnt, list2, cnt2);
    vq_scan<1><<<512, 512, 0, stream>>>(X, eimg, Arow, idx, list2, cnt2, keys, s1buf,
                                        cand, ccnt, list2, cnt2);
    vq_refine_cand<<<1024, 256, 0, stream>>>(X, E, Arow, keys, cand, ccnt);
    vq_apply<<<128, 256, 0, stream>>>(keys, list, cnt, idx);
    vq_out<<<N_ROWS / 4, 256, 0, stream>>>(X, E, idx, out, part);
    vq_loss<<<1, 256, 0, stream>>>(part, out);
}

// Round 15
// 485.576 us; speedup vs baseline: 2.4719x; 2.4719x over previous
//
#include <hip/hip_runtime.h>

#define N_ROWS 32768
#define DIM 256
#define N_CODES 8192
#define OUT_Q 8388608        // N_ROWS*DIM
#define OUT_LOSS 8388608
#define OUT_IDX 8388609
#define FLAG_GAP 7e-5f       // >= 2 grid cells (g=3.05e-5) + 2*split-err -> safe (8 runs proven)
#define GAP3 1e-4f           // rescan-needed threshold on s3 (wider, safety margin)
#define CAND_CAP 262144

// ws layout (bytes)
#define WS_AROW 0            // 32768 f32
#define WS_IDX  131072       // 32768 i32
#define WS_LIST 262144       // 32768 i32  (all flagged rows -> vq_apply)
#define WS_CNT  393216       // i32 flagcnt; +8 i32 cnt2; +16 i32 candcnt
#define WS_S1   393472       // 32768 f32
#define WS_KEYS 524544       // 32768 u64
#define WS_PART 524544       // aliased onto KEYS (keys dead before vq_out writes partials)
#define WS_EIMG 1048576      // 8MB E-image if ws allows, else d_out scratch

typedef __attribute__((ext_vector_type(8))) short short8x;
typedef __attribute__((ext_vector_type(4))) float f32x4;
typedef unsigned long long u64;

__device__ __forceinline__ u64 umin64(u64 a, u64 b) { return a < b ? a : b; }
// order-preserving float->uint map
__device__ __forceinline__ unsigned fkey(float f) {
    unsigned b = __float_as_uint(f);
    return b ^ (unsigned)(((int)b >> 31) | 0x80000000);
}
__device__ __forceinline__ float fkeyinv(unsigned u) {
    unsigned b = (u >> 31) ? (u ^ 0x80000000u) : ~u;
    return __uint_as_float(b);
}
__device__ __forceinline__ unsigned short bf16rne(float f) {
    unsigned u = __float_as_uint(f);
    return (unsigned short)((u + 0x7fff + ((u >> 16) & 1)) >> 16);
}
// merge two sorted u64 triples (a1<=a2<=a3), (b1<=b2<=b3) -> 3 smallest (in place in k1..k3)
__device__ __forceinline__ void triple_merge(u64& k1, u64& k2, u64& k3, u64 o1, u64 o2, u64 o3) {
    bool c = o1 < k1;
    u64 A1 = c ? o1 : k1, A2 = c ? o2 : k2, A3 = c ? o3 : k3;
    u64 B1 = c ? k1 : o1, B2 = c ? k2 : o2;
    bool d = B1 < A2;
    k1 = A1;
    k2 = d ? B1 : A2;
    k3 = d ? umin64(A2, B2) : umin64(A3, B1);
}

// ---------------- Kernel P: E -> bf16 h/l split, reg-load frag-linear image ----------------
// 256 chunks (tile 0..31 x S 0..7) of 32KB; chunk = 8 wave-blocks of 4KB.
// Fragment layout: off = ci*32768 + wv*4096 + c*1024 + lane*16 (h), +2048 (l)
//   lane holds code = tile*256 + wv*32 + c*16 + (lane&15), k = S*32 + (lane>>4)*8 + j
__global__ void vq_prepE(const float* __restrict__ E, char* __restrict__ Eimg) {
    int t = blockIdx.x * 256 + threadIdx.x;   // 0..262143
    int ci = t >> 10;
    int u = t & 1023;
    int wv = u >> 7;
    int v = u & 127;
    int c = v >> 6, lane = v & 63;
    int tile = ci >> 3, S = ci & 7;
    int code = tile * 256 + wv * 32 + c * 16 + (lane & 15);
    int k0 = S * 32 + (lane >> 4) * 8;
    const float* src = E + (size_t)code * DIM + k0;
    unsigned short h[8], l[8];
#pragma unroll
    for (int j = 0; j < 8; ++j) {
        float vv = src[j];
        h[j] = bf16rne(vv);
        float hf = __uint_as_float((unsigned)h[j] << 16);
        l[j] = bf16rne(vv - hf);
    }
    short8x H, L;
#pragma unroll
    for (int j = 0; j < 8; ++j) { H[j] = (short)h[j]; L[j] = (short)l[j]; }
    char* dst = Eimg + (size_t)ci * 32768 + wv * 4096 + c * 1024 + lane * 16;
    *(short8x*)dst = H;            // h plane
    *(short8x*)(dst + 2048) = L;   // l plane
}

// ---------------- Kernel A: per-row ||x||^2 in fp64 -> fp32 ----------------
__global__ void vq_rowA(const float* __restrict__ X, float* __restrict__ Arow) {
    int row = blockIdx.x * 4 + (threadIdx.x >> 6);
    int lane = threadIdx.x & 63;
    const float4 v = *((const float4*)(X + (size_t)row * DIM + lane * 4));
    double s = (double)v.x * v.x + (double)v.y * v.y + (double)v.z * v.z + (double)v.w * v.w;
#pragma unroll
    for (int m = 1; m < 64; m <<= 1) s += __shfl_xor(s, m, 64);
    if (lane == 0) Arow[row] = (float)s;
}

// ------- Kernel B: MFMA split-bf16 distance scan; E in REGISTERS, copy-free A/B
//   rotation (S-loop step 2), s_setprio(1) around MFMA clusters (T5), X in LDS.
//   MODE 0: all rows, TOP-3 argmin; flag rows (s2-s1<GAP); emit {i1,i2} candidates;
//           rows with s3-s1<=GAP3 go to rescan list2.
//   MODE 1: rescan rows from list2; task = (group, 2-tile range); emit cands <= s1+GAP.
template <int MODE>
__global__ __launch_bounds__(512, 1) void vq_scan(
    const float* __restrict__ X, const char* __restrict__ Eimg,
    const float* __restrict__ Arow, int* __restrict__ ws_idx,
    int* __restrict__ flaglist, int* __restrict__ flagcnt,
    u64* __restrict__ keybuf, float* __restrict__ s1buf,
    unsigned* __restrict__ cand, int* __restrict__ candcnt,
    int* __restrict__ list2, int* __restrict__ cnt2) {
    __shared__ alignas(16) unsigned short Xs[32768];   // 64KB: h plane, l plane
    __shared__ int rows_s[64];             // gathered row ids (MODE 1)

    const int tid = threadIdx.x;
    const int lane = tid & 63, wv = tid >> 6;      // wv 0..7
    const int l15 = lane & 15, sub = lane >> 4;

    const int cnt = (MODE == 1) ? *flagcnt : 0;
    const int ntasks = (MODE == 1) ? ((cnt + 63) >> 6) * 16 : 0;

    const char* const eimgw = Eimg + wv * 4096 + lane * 16;   // this wave+lane's E base

    float r1v[4][4], r2v[4][4], r3v[4][4];
    int c1v[4][4], c2v[4][4];
    if constexpr (MODE == 0) {
#pragma unroll
        for (int f = 0; f < 4; ++f)
#pragma unroll
            for (int g = 0; g < 4; ++g) {
                r1v[f][g] = 3.4e38f; r2v[f][g] = 3.4e38f; r3v[f][g] = 3.4e38f;
                c1v[f][g] = 0; c2v[f][g] = 0;
            }
    }

    int task = blockIdx.x;
    while (true) {
        int t0, t1, r0;
        if constexpr (MODE == 1) {
            if (task >= ntasks) break;
            int grp = task >> 4;
            int rng = task & 15;
            t0 = rng * 2; t1 = t0 + 2;
            r0 = 0;
            __syncthreads();   // all waves done with previous task's Xs/rows_s
            if (tid < 64) {
                int s = grp * 64 + tid;
                rows_s[tid] = flaglist[s < cnt ? s : cnt - 1];
            }
            __syncthreads();
        } else {
            t0 = 0; t1 = 32;
            r0 = blockIdx.x * 64;
        }
        const int cend = t1 * 8;

        // prologue: load first E chunk's fragments into register set A
        short8x cuA0, cuA1, cuA2, cuA3, cuB0, cuB1, cuB2, cuB3;
        {
            const char* p = eimgw + (size_t)(t0 * 8) * 32768;
            cuA0 = *(const short8x*)p;            // h, c=0
            cuA1 = *(const short8x*)(p + 1024);   // h, c=1
            cuA2 = *(const short8x*)(p + 2048);   // l, c=0
            cuA3 = *(const short8x*)(p + 3072);   // l, c=1
        }
        // stage X tile with in-register f32 -> bf16 h/l conversion
#pragma unroll
        for (int i = 0; i < 4; ++i) {
            int ci = tid + i * 512;                // 0..2047
            int q = ci >> 6, r = ci & 63;
            int grow = (MODE == 1) ? rows_s[r] : r0 + r;
            const float* src = X + (size_t)grow * DIM + q * 8;
            unsigned short h[8], l[8];
#pragma unroll
            for (int j = 0; j < 8; ++j) {
                float v = src[j];
                h[j] = bf16rne(v);
                float hf = __uint_as_float((unsigned)h[j] << 16);
                l[j] = bf16rne(v - hf);
            }
            short8x H, L;
#pragma unroll
            for (int j = 0; j < 8; ++j) { H[j] = (short)h[j]; L[j] = (short)l[j]; }
            *(short8x*)((char*)Xs + q * 1024 + r * 16) = H;
            *(short8x*)((char*)Xs + 32768 + q * 1024 + r * 16) = L;
        }

        float A_r[4][4], s1v[4][4];
        int rid[4][4];
#pragma unroll
        for (int f = 0; f < 4; ++f)
#pragma unroll
            for (int g = 0; g < 4; ++g) {
                int rr = (MODE == 1) ? rows_s[f * 16 + sub * 4 + g] : r0 + f * 16 + sub * 4 + g;
                A_r[f][g] = Arow[rr];
                if constexpr (MODE == 1) { s1v[f][g] = s1buf[rr]; rid[f][g] = rr; }
            }

        __syncthreads();   // X visible to all waves

#pragma unroll 1
        for (int t = t0; t < t1; ++t) {
            f32x4 acc[4][2];
#pragma unroll
            for (int f = 0; f < 4; ++f)
#pragma unroll
                for (int c = 0; c < 2; ++c) acc[f][c] = (f32x4){0.f, 0.f, 0.f, 0.f};

#pragma unroll 1
            for (int S = 0; S < 8; S += 2) {
                const char* xb = (const char*)Xs;
                // ---- even sub-step: consume cuA, prefetch directly into cuB ----
                {
                    const int ci = t * 8 + S;
                    const int cin = (ci + 1 < cend) ? ci + 1 : ci;
                    const char* p = eimgw + (size_t)cin * 32768;
                    cuB0 = *(const short8x*)p;
                    cuB1 = *(const short8x*)(p + 1024);
                    cuB2 = *(const short8x*)(p + 2048);
                    cuB3 = *(const short8x*)(p + 3072);

                    short8x ah[4], al[4];
#pragma unroll
                    for (int f = 0; f < 4; ++f) {
                        int off = (S * 4 + sub) * 1024 + f * 256 + l15 * 16;
                        ah[f] = *(const short8x*)(xb + off);
                        al[f] = *(const short8x*)(xb + 32768 + off);
                    }
                    __builtin_amdgcn_s_setprio(1);
#pragma unroll
                    for (int f = 0; f < 4; ++f) {
                        f32x4 a0 = acc[f][0];
                        a0 = __builtin_amdgcn_mfma_f32_16x16x32_bf16(al[f], cuA0, a0, 0, 0, 0);
                        a0 = __builtin_amdgcn_mfma_f32_16x16x32_bf16(ah[f], cuA2, a0, 0, 0, 0);
                        a0 = __builtin_amdgcn_mfma_f32_16x16x32_bf16(ah[f], cuA0, a0, 0, 0, 0);
                        acc[f][0] = a0;
                        f32x4 a1 = acc[f][1];
                        a1 = __builtin_amdgcn_mfma_f32_16x16x32_bf16(al[f], cuA1, a1, 0, 0, 0);
                        a1 = __builtin_amdgcn_mfma_f32_16x16x32_bf16(ah[f], cuA3, a1, 0, 0, 0);
                        a1 = __builtin_amdgcn_mfma_f32_16x16x32_bf16(ah[f], cuA1, a1, 0, 0, 0);
                        acc[f][1] = a1;
                    }
                    __builtin_amdgcn_s_setprio(0);
                }
                // ---- odd sub-step: consume cuB, prefetch directly into cuA ----
                {
                    const int ci = t * 8 + S + 1;
                    const int cin = (ci + 1 < cend) ? ci + 1 : ci;
                    const char* p = eimgw + (size_t)cin * 32768;
                    cuA0 = *(const short8x*)p;
                    cuA1 = *(const short8x*)(p + 1024);
                    cuA2 = *(const short8x*)(p + 2048);
                    cuA3 = *(const short8x*)(p + 3072);

                    short8x ah[4], al[4];
#pragma unroll
                    for (int f = 0; f < 4; ++f) {
                        int off = ((S + 1) * 4 + sub) * 1024 + f * 256 + l15 * 16;
                        ah[f] = *(const short8x*)(xb + off);
                        al[f] = *(const short8x*)(xb + 32768 + off);
                    }
                    __builtin_amdgcn_s_setprio(1);
#pragma unroll
                    for (int f = 0; f < 4; ++f) {
                        f32x4 a0 = acc[f][0];
                        a0 = __builtin_amdgcn_mfma_f32_16x16x32_bf16(al[f], cuB0, a0, 0, 0, 0);
                        a0 = __builtin_amdgcn_mfma_f32_16x16x32_bf16(ah[f], cuB2, a0, 0, 0, 0);
                        a0 = __builtin_amdgcn_mfma_f32_16x16x32_bf16(ah[f], cuB0, a0, 0, 0, 0);
                        acc[f][0] = a0;
                        f32x4 a1 = acc[f][1];
                        a1 = __builtin_amdgcn_mfma_f32_16x16x32_bf16(al[f], cuB1, a1, 0, 0, 0);
                        a1 = __builtin_amdgcn_mfma_f32_16x16x32_bf16(ah[f], cuB3, a1, 0, 0, 0);
                        a1 = __builtin_amdgcn_mfma_f32_16x16x32_bf16(ah[f], cuB1, a1, 0, 0, 0);
                        acc[f][1] = a1;
                    }
                    __builtin_amdgcn_s_setprio(0);
                }
            }

            const int cbase = t * 256 + wv * 32 + l15;   // + c*16
            if constexpr (MODE == 0) {
                // fold tile pair into running top-3 (values + idx for top-2)
#pragma unroll
                for (int f = 0; f < 4; ++f)
#pragma unroll
                    for (int g = 0; g < 4; ++g) {
                        float v0 = fmaf(-2.0f, acc[f][0][g], A_r[f][g]);
                        float v1 = fmaf(-2.0f, acc[f][1][g], A_r[f][g]);
                        bool sw = v1 < v0;
                        float lo = sw ? v1 : v0, hi = sw ? v0 : v1;
                        int ilo = sw ? cbase + 16 : cbase;
                        int ihi = sw ? cbase : cbase + 16;
                        bool cond = lo < r1v[f][g];
                        float A2 = cond ? hi : r2v[f][g];
                        float A3 = cond ? 3.4e38f : r3v[f][g];
                        float B1 = cond ? r1v[f][g] : lo;
                        float B2 = cond ? r2v[f][g] : hi;
                        int iA2 = cond ? ihi : c2v[f][g];
                        int iB1 = cond ? c1v[f][g] : ilo;
                        r1v[f][g] = cond ? lo : r1v[f][g];
                        c1v[f][g] = cond ? ilo : c1v[f][g];
                        bool d = B1 < A2;
                        r2v[f][g] = d ? B1 : A2;
                        c2v[f][g] = d ? iB1 : iA2;
                        r3v[f][g] = d ? fminf(A2, B2) : fminf(A3, B1);
                    }
            } else {
#pragma unroll
                for (int f = 0; f < 4; ++f)
#pragma unroll
                    for (int g = 0; g < 4; ++g) {
                        float thr = s1v[f][g] + FLAG_GAP;
#pragma unroll
                        for (int c = 0; c < 2; ++c) {
                            float v = fmaf(-2.0f, acc[f][c][g], A_r[f][g]);
                            if (v <= thr) {
                                int slot = atomicAdd(candcnt, 1);
                                if (slot < CAND_CAP)
                                    cand[slot] = ((unsigned)rid[f][g] << 13) |
                                                 (unsigned)(cbase + c * 16);
                            }
                        }
                    }
            }
        }

        if constexpr (MODE == 0) break;
        else task += gridDim.x;
    }

    if constexpr (MODE == 0) {
        __syncthreads();   // all waves done reading Xs before aliasing it as red[]
        u64* red = (u64*)Xs;   // [8 waves][64 rows][3] = 12KB
#pragma unroll
        for (int f = 0; f < 4; ++f)
#pragma unroll
            for (int g = 0; g < 4; ++g) {
                u64 k1 = ((u64)fkey(r1v[f][g]) << 32) | (unsigned)c1v[f][g];
                u64 k2 = ((u64)fkey(r2v[f][g]) << 32) | (unsigned)c2v[f][g];
                u64 k3 = ((u64)fkey(r3v[f][g]) << 32) | 0x1fffu;   // idx unused
#pragma unroll
                for (int m = 1; m < 16; m <<= 1) {
                    u64 o1 = __shfl_xor(k1, m, 64);
                    u64 o2 = __shfl_xor(k2, m, 64);
                    u64 o3 = __shfl_xor(k3, m, 64);
                    triple_merge(k1, k2, k3, o1, o2, o3);
                }
                if (l15 == 0) {
                    int row64 = f * 16 + sub * 4 + g;
                    red[(wv * 64 + row64) * 3 + 0] = k1;
                    red[(wv * 64 + row64) * 3 + 1] = k2;
                    red[(wv * 64 + row64) * 3 + 2] = k3;
                }
            }
        __syncthreads();
        if (tid < 64) {
            u64 K1 = red[tid * 3 + 0], K2 = red[tid * 3 + 1], K3 = red[tid * 3 + 2];
#pragma unroll
            for (int w = 1; w < 8; ++w) {
                triple_merge(K1, K2, K3,
                             red[(w * 64 + tid) * 3 + 0],
                             red[(w * 64 + tid) * 3 + 1],
                             red[(w * 64 + tid) * 3 + 2]);
            }
            int r = blockIdx.x * 64 + tid;
            ws_idx[r] = (int)(unsigned)(K1 & 0xffffffffull);
            float s1 = fkeyinv((unsigned)(K1 >> 32));
            float s2 = fkeyinv((unsigned)(K2 >> 32));
            float s3 = fkeyinv((unsigned)(K3 >> 32));
            s1buf[r] = s1;
            if (s2 - s1 < FLAG_GAP) {
                keybuf[r] = ~0ull;
                flaglist[atomicAdd(flagcnt, 1)] = r;
                int cs = atomicAdd(candcnt, 2);
                if (cs + 1 < CAND_CAP) {
                    cand[cs]     = ((unsigned)r << 13) | (unsigned)(K1 & 8191ull);
                    cand[cs + 1] = ((unsigned)r << 13) | (unsigned)(K2 & 8191ull);
                }
                if (s3 - s1 <= GAP3) list2[atomicAdd(cnt2, 1)] = r;
            }
        }
    }
}

// ------- Kernel C: fp64 np-semantics scoring of candidates, atomicMin merge -------
__global__ void vq_refine_cand(const float* __restrict__ X, const float* __restrict__ E,
                               const float* __restrict__ Arow, u64* __restrict__ keybuf,
                               const unsigned* __restrict__ cand,
                               const int* __restrict__ candcnt) {
    int cnt2 = *candcnt;
    cnt2 = cnt2 < CAND_CAP ? cnt2 : CAND_CAP;
    const int gw = (blockIdx.x * 256 + threadIdx.x) >> 6;   // global wave id
    const int nw = gridDim.x * 4;
    const int lane = threadIdx.x & 63;
    for (int i = gw; i < cnt2; i += nw) {
        unsigned p = cand[i];
        int row = (int)(p >> 13), code = (int)(p & 8191);
        float4 xv = *(const float4*)(X + (size_t)row * DIM + lane * 4);
        float4 ev = *(const float4*)(E + (size_t)code * DIM + lane * 4);
        double s = (double)xv.x * ev.x + (double)xv.y * ev.y +
                   (double)xv.z * ev.z + (double)xv.w * ev.w;
#pragma unroll
        for (int m = 1; m < 64; m <<= 1) s += __shfl_xor(s, m, 64);
        if (lane == 0) {
            float m32 = (float)s;
            float scr = fmaf(-2.0f, m32, Arow[row]);
            u64 key = ((u64)fkey(scr) << 32) | (unsigned)code;
            atomicMin(keybuf + row, key);
        }
    }
}

// ------- Kernel C2: apply refined winners (defensive: skip untouched sentinel) -------
__global__ void vq_apply(const u64* __restrict__ keybuf, const int* __restrict__ flaglist,
                         const int* __restrict__ flagcnt, int* __restrict__ ws_idx) {
    int s = blockIdx.x * 256 + threadIdx.x;
    if (s < *flagcnt) {
        int r = flaglist[s];
        u64 k = keybuf[r];
        if (k != ~0ull) ws_idx[r] = (int)(unsigned)(k & 0xffffffffull);
    }
}

// ---------------- Kernel D: gather quantized (ST-mimic), loss partials ----------------
__global__ void vq_out(const float* __restrict__ X, const float* __restrict__ E,
                       const int* __restrict__ ws_idx, float* __restrict__ out,
                       float* __restrict__ partials) {
    const int r = (blockIdx.x * 256 + threadIdx.x) >> 6;
    const int lane = threadIdx.x & 63;
    int idx = ws_idx[r];
    idx = idx < 0 ? 0 : (idx > N_CODES - 1 ? N_CODES - 1 : idx);   // defensive clamp
    float4 e = *((const float4*)(E + (size_t)idx * DIM + lane * 4));
    float4 x = *((const float4*)(X + (size_t)r * DIM + lane * 4));
    float dx = e.x - x.x, dy = e.y - x.y, dz = e.z - x.z, dw = e.w - x.w;
    float4 o;
    o.x = x.x + dx; o.y = x.y + dy; o.z = x.z + dz; o.w = x.w + dw;
    *((float4*)(out + (size_t)r * DIM + lane * 4)) = o;
    float s = dx * dx + dy * dy + dz * dz + dw * dw;
#pragma unroll
    for (int m = 1; m < 64; m <<= 1) s += __shfl_xor(s, m, 64);
    if (lane == 0) {
        partials[r] = s;
        out[OUT_IDX + r] = (float)idx;
    }
}

// ---------------- Kernel E: deterministic loss reduction ----------------
__global__ void vq_loss(const float* __restrict__ partials, float* __restrict__ out) {
    __shared__ double sred[4];
    double s = 0.0;
    for (int i = threadIdx.x; i < N_ROWS; i += 256) s += (double)partials[i];
#pragma unroll
    for (int m = 1; m < 64; m <<= 1) s += __shfl_xor(s, m, 64);
    if ((threadIdx.x & 63) == 0) sred[threadIdx.x >> 6] = s;
    __syncthreads();
    if (threadIdx.x == 0) {
        double t = sred[0] + sred[1] + sred[2] + sred[3];
        out[OUT_LOSS] = (float)(2.0 * t / (double)OUT_Q);
    }
}

extern "C" void kernel_launch(void* const* d_in, const int* in_sizes, int n_in,
                              void* d_out, int out_size, void* d_ws, size_t ws_size,
                              hipStream_t stream) {
    const float* X = (const float*)d_in[0];
    const float* E = (const float*)d_in[1];
    float* out = (float*)d_out;
    char* ws = (char*)d_ws;

    float* Arow = (float*)(ws + WS_AROW);
    int* idx = (int*)(ws + WS_IDX);
    int* list = (int*)(ws + WS_LIST);
    int* cnt = (int*)(ws + WS_CNT);
    int* cnt2 = (int*)(ws + WS_CNT + 8);
    int* ccnt = (int*)(ws + WS_CNT + 16);
    float* s1buf = (float*)(ws + WS_S1);
    u64* keys = (u64*)(ws + WS_KEYS);
    float* part = (float*)(ws + WS_PART);   // aliased onto keys (dead by then)
    char* eimg = (ws_size >= (size_t)(WS_EIMG + 8 * 1024 * 1024)) ? (ws + WS_EIMG) : (char*)d_out;
    unsigned* cand = (unsigned*)((char*)d_out + (16 << 20));   // [16MB,17MB) of d_out
    int* list2 = (int*)((char*)d_out + (17 << 20));            // [17MB,17.125MB) of d_out
    // both scratch regions are overwritten by vq_out afterwards

    hipMemsetAsync(ws + WS_CNT, 0, 32, stream);   // zero flagcnt + cnt2 + candcnt
    vq_prepE<<<1024, 256, 0, stream>>>(E, eimg);
    vq_rowA<<<N_ROWS / 4, 256, 0, stream>>>(X, Arow);
    vq_scan<0><<<N_ROWS / 64, 512, 0, stream>>>(X, eimg, Arow, idx, list, cnt, keys, s1buf,
                                                cand, ccnt, list2, cnt2);
    vq_scan<1><<<512, 512, 0, stream>>>(X, eimg, Arow, idx, list2, cnt2, keys, s1buf,
                                        cand, ccnt, list2, cnt2);
    vq_refine_cand<<<1024, 256, 0, stream>>>(X, E, Arow, keys, cand, ccnt);
    vq_apply<<<128, 256, 0, stream>>>(keys, list, cnt, idx);
    vq_out<<<N_ROWS / 4, 256, 0, stream>>>(X, E, idx, out, part);
    vq_loss<<<1, 256, 0, stream>>>(part, out);
}

// Round 16
// 464.215 us; speedup vs baseline: 2.5857x; 1.0460x over previous
//
#include <hip/hip_runtime.h>

#define N_ROWS 32768
#define DIM 256
#define N_CODES 8192
#define OUT_Q 8388608        // N_ROWS*DIM
#define OUT_LOSS 8388608
#define OUT_IDX 8388609
#define FLAG_GAP 7e-5f       // >= 2 grid cells (g=3.05e-5) + 2*split-err -> safe (9 runs proven)
#define GAP3 1e-4f           // rescan-needed threshold on s3 (wider, safety margin)
#define CAND_CAP 262144

// ws layout (bytes)
#define WS_AROW 0            // 32768 f32
#define WS_IDX  131072       // 32768 i32
#define WS_LIST 262144       // 32768 i32  (all flagged rows -> vq_apply)
#define WS_CNT  393216       // i32 flagcnt; +8 i32 cnt2; +16 i32 candcnt
#define WS_S1   393472       // 32768 f32
#define WS_KEYS 524544       // 32768 u64
#define WS_PART 524544       // aliased onto KEYS (keys dead before vq_out writes partials)
#define WS_EIMG 1048576      // 8MB E-image if ws allows, else d_out scratch

typedef __attribute__((ext_vector_type(8))) short short8x;
typedef __attribute__((ext_vector_type(4))) float f32x4;
typedef unsigned long long u64;

__device__ __forceinline__ u64 umin64(u64 a, u64 b) { return a < b ? a : b; }
// order-preserving float->uint map
__device__ __forceinline__ unsigned fkey(float f) {
    unsigned b = __float_as_uint(f);
    return b ^ (unsigned)(((int)b >> 31) | 0x80000000);
}
__device__ __forceinline__ float fkeyinv(unsigned u) {
    unsigned b = (u >> 31) ? (u ^ 0x80000000u) : ~u;
    return __uint_as_float(b);
}
__device__ __forceinline__ unsigned short bf16rne(float f) {
    unsigned u = __float_as_uint(f);
    return (unsigned short)((u + 0x7fff + ((u >> 16) & 1)) >> 16);
}
// merge two sorted u64 triples (a1<=a2<=a3), (b1<=b2<=b3) -> 3 smallest (in place in k1..k3)
__device__ __forceinline__ void triple_merge(u64& k1, u64& k2, u64& k3, u64 o1, u64 o2, u64 o3) {
    bool c = o1 < k1;
    u64 A1 = c ? o1 : k1, A2 = c ? o2 : k2, A3 = c ? o3 : k3;
    u64 B1 = c ? k1 : o1, B2 = c ? k2 : o2;
    bool d = B1 < A2;
    k1 = A1;
    k2 = d ? B1 : A2;
    k3 = d ? umin64(A2, B2) : umin64(A3, B1);
}

// ---------------- Kernel P: E -> bf16 h/l split, reg-load frag-linear image ----------------
// 256 chunks (tile 0..31 x S 0..7) of 32KB; chunk = 8 wave-blocks of 4KB.
// Fragment layout: off = ci*32768 + wv*4096 + c*1024 + lane*16 (h), +2048 (l)
//   lane holds code = tile*256 + wv*32 + c*16 + (lane&15), k = S*32 + (lane>>4)*8 + j
__global__ void vq_prepE(const float* __restrict__ E, char* __restrict__ Eimg) {
    int t = blockIdx.x * 256 + threadIdx.x;   // 0..262143
    int ci = t >> 10;
    int u = t & 1023;
    int wv = u >> 7;
    int v = u & 127;
    int c = v >> 6, lane = v & 63;
    int tile = ci >> 3, S = ci & 7;
    int code = tile * 256 + wv * 32 + c * 16 + (lane & 15);
    int k0 = S * 32 + (lane >> 4) * 8;
    const float* src = E + (size_t)code * DIM + k0;
    unsigned short h[8], l[8];
#pragma unroll
    for (int j = 0; j < 8; ++j) {
        float vv = src[j];
        h[j] = bf16rne(vv);
        float hf = __uint_as_float((unsigned)h[j] << 16);
        l[j] = bf16rne(vv - hf);
    }
    short8x H, L;
#pragma unroll
    for (int j = 0; j < 8; ++j) { H[j] = (short)h[j]; L[j] = (short)l[j]; }
    char* dst = Eimg + (size_t)ci * 32768 + wv * 4096 + c * 1024 + lane * 16;
    *(short8x*)dst = H;            // h plane
    *(short8x*)(dst + 2048) = L;   // l plane
}

// ---------------- Kernel A: per-row ||x||^2 in fp64 -> fp32 ----------------
__global__ void vq_rowA(const float* __restrict__ X, float* __restrict__ Arow) {
    int row = blockIdx.x * 4 + (threadIdx.x >> 6);
    int lane = threadIdx.x & 63;
    const float4 v = *((const float4*)(X + (size_t)row * DIM + lane * 4));
    double s = (double)v.x * v.x + (double)v.y * v.y + (double)v.z * v.z + (double)v.w * v.w;
#pragma unroll
    for (int m = 1; m < 64; m <<= 1) s += __shfl_xor(s, m, 64);
    if (lane == 0) Arow[row] = (float)s;
}

// ------- Kernel B: MFMA split-bf16 distance scan; E in REGISTERS, parity-static A/B
//   sets, S-loop FULLY UNROLLED (immediate LDS offsets, no copy-rotation),
//   launch_bounds(512,2) -> 256-VGPR budget (prevents r10-style spill-to-128).
//   MODE 0: all rows, TOP-3 argmin; flag rows (s2-s1<GAP); emit {i1,i2} candidates;
//           rows with s3-s1<=GAP3 go to rescan list2.
//   MODE 1: rescan rows from list2; task = (group, 2-tile range); emit cands <= s1+GAP.
template <int MODE>
__global__ __launch_bounds__(512, 2) void vq_scan(
    const float* __restrict__ X, const char* __restrict__ Eimg,
    const float* __restrict__ Arow, int* __restrict__ ws_idx,
    int* __restrict__ flaglist, int* __restrict__ flagcnt,
    u64* __restrict__ keybuf, float* __restrict__ s1buf,
    unsigned* __restrict__ cand, int* __restrict__ candcnt,
    int* __restrict__ list2, int* __restrict__ cnt2) {
    __shared__ alignas(16) unsigned short Xs[32768];   // 64KB: h plane, l plane
    __shared__ int rows_s[64];             // gathered row ids (MODE 1)

    const int tid = threadIdx.x;
    const int lane = tid & 63, wv = tid >> 6;      // wv 0..7
    const int l15 = lane & 15, sub = lane >> 4;

    const int cnt = (MODE == 1) ? *flagcnt : 0;
    const int ntasks = (MODE == 1) ? ((cnt + 63) >> 6) * 16 : 0;

    const char* const eimgw = Eimg + wv * 4096 + lane * 16;   // this wave+lane's E base

    float r1v[4][4], r2v[4][4], r3v[4][4];
    int c1v[4][4], c2v[4][4];
    if constexpr (MODE == 0) {
#pragma unroll
        for (int f = 0; f < 4; ++f)
#pragma unroll
            for (int g = 0; g < 4; ++g) {
                r1v[f][g] = 3.4e38f; r2v[f][g] = 3.4e38f; r3v[f][g] = 3.4e38f;
                c1v[f][g] = 0; c2v[f][g] = 0;
            }
    }

    int task = blockIdx.x;
    while (true) {
        int t0, t1, r0;
        if constexpr (MODE == 1) {
            if (task >= ntasks) break;
            int grp = task >> 4;
            int rng = task & 15;
            t0 = rng * 2; t1 = t0 + 2;
            r0 = 0;
            __syncthreads();   // all waves done with previous task's Xs/rows_s
            if (tid < 64) {
                int s = grp * 64 + tid;
                rows_s[tid] = flaglist[s < cnt ? s : cnt - 1];
            }
            __syncthreads();
        } else {
            t0 = 0; t1 = 32;
            r0 = blockIdx.x * 64;
        }
        const int cend = t1 * 8;

        // prologue: load first E chunk's fragments into register set A
        short8x cuA0, cuA1, cuA2, cuA3, cuB0, cuB1, cuB2, cuB3;
        {
            const char* p = eimgw + (size_t)(t0 * 8) * 32768;
            cuA0 = *(const short8x*)p;            // h, c=0
            cuA1 = *(const short8x*)(p + 1024);   // h, c=1
            cuA2 = *(const short8x*)(p + 2048);   // l, c=0
            cuA3 = *(const short8x*)(p + 3072);   // l, c=1
        }
        // stage X tile with in-register f32 -> bf16 h/l conversion
#pragma unroll
        for (int i = 0; i < 4; ++i) {
            int ci = tid + i * 512;                // 0..2047
            int q = ci >> 6, r = ci & 63;
            int grow = (MODE == 1) ? rows_s[r] : r0 + r;
            const float* src = X + (size_t)grow * DIM + q * 8;
            unsigned short h[8], l[8];
#pragma unroll
            for (int j = 0; j < 8; ++j) {
                float v = src[j];
                h[j] = bf16rne(v);
                float hf = __uint_as_float((unsigned)h[j] << 16);
                l[j] = bf16rne(v - hf);
            }
            short8x H, L;
#pragma unroll
            for (int j = 0; j < 8; ++j) { H[j] = (short)h[j]; L[j] = (short)l[j]; }
            *(short8x*)((char*)Xs + q * 1024 + r * 16) = H;
            *(short8x*)((char*)Xs + 32768 + q * 1024 + r * 16) = L;
        }

        float A_r[4][4], s1v[4][4];
        int rid[4][4];
#pragma unroll
        for (int f = 0; f < 4; ++f)
#pragma unroll
            for (int g = 0; g < 4; ++g) {
                int rr = (MODE == 1) ? rows_s[f * 16 + sub * 4 + g] : r0 + f * 16 + sub * 4 + g;
                A_r[f][g] = Arow[rr];
                if constexpr (MODE == 1) { s1v[f][g] = s1buf[rr]; rid[f][g] = rr; }
            }

        __syncthreads();   // X visible to all waves

#pragma unroll 1
        for (int t = t0; t < t1; ++t) {
            f32x4 acc[4][2];
#pragma unroll
            for (int f = 0; f < 4; ++f)
#pragma unroll
                for (int c = 0; c < 2; ++c) acc[f][c] = (f32x4){0.f, 0.f, 0.f, 0.f};

#pragma unroll
            for (int S = 0; S < 8; S += 2) {
                const char* xb = (const char*)Xs;
                // ---- even sub-step: consume cuA, prefetch directly into cuB ----
                {
                    const int ci = t * 8 + S;
                    const int cin = (ci + 1 < cend) ? ci + 1 : ci;
                    const char* p = eimgw + (size_t)cin * 32768;
                    cuB0 = *(const short8x*)p;
                    cuB1 = *(const short8x*)(p + 1024);
                    cuB2 = *(const short8x*)(p + 2048);
                    cuB3 = *(const short8x*)(p + 3072);

                    short8x ah[4], al[4];
#pragma unroll
                    for (int f = 0; f < 4; ++f) {
                        int off = (S * 4 + sub) * 1024 + f * 256 + l15 * 16;
                        ah[f] = *(const short8x*)(xb + off);
                        al[f] = *(const short8x*)(xb + 32768 + off);
                    }
                    __builtin_amdgcn_s_setprio(1);
#pragma unroll
                    for (int f = 0; f < 4; ++f) {
                        f32x4 a0 = acc[f][0];
                        a0 = __builtin_amdgcn_mfma_f32_16x16x32_bf16(al[f], cuA0, a0, 0, 0, 0);
                        a0 = __builtin_amdgcn_mfma_f32_16x16x32_bf16(ah[f], cuA2, a0, 0, 0, 0);
                        a0 = __builtin_amdgcn_mfma_f32_16x16x32_bf16(ah[f], cuA0, a0, 0, 0, 0);
                        acc[f][0] = a0;
                        f32x4 a1 = acc[f][1];
                        a1 = __builtin_amdgcn_mfma_f32_16x16x32_bf16(al[f], cuA1, a1, 0, 0, 0);
                        a1 = __builtin_amdgcn_mfma_f32_16x16x32_bf16(ah[f], cuA3, a1, 0, 0, 0);
                        a1 = __builtin_amdgcn_mfma_f32_16x16x32_bf16(ah[f], cuA1, a1, 0, 0, 0);
                        acc[f][1] = a1;
                    }
                    __builtin_amdgcn_s_setprio(0);
                }
                // ---- odd sub-step: consume cuB, prefetch directly into cuA ----
                {
                    const int ci = t * 8 + S + 1;
                    const int cin = (ci + 1 < cend) ? ci + 1 : ci;
                    const char* p = eimgw + (size_t)cin * 32768;
                    cuA0 = *(const short8x*)p;
                    cuA1 = *(const short8x*)(p + 1024);
                    cuA2 = *(const short8x*)(p + 2048);
                    cuA3 = *(const short8x*)(p + 3072);

                    short8x ah[4], al[4];
#pragma unroll
                    for (int f = 0; f < 4; ++f) {
                        int off = ((S + 1) * 4 + sub) * 1024 + f * 256 + l15 * 16;
                        ah[f] = *(const short8x*)(xb + off);
                        al[f] = *(const short8x*)(xb + 32768 + off);
                    }
                    __builtin_amdgcn_s_setprio(1);
#pragma unroll
                    for (int f = 0; f < 4; ++f) {
                        f32x4 a0 = acc[f][0];
                        a0 = __builtin_amdgcn_mfma_f32_16x16x32_bf16(al[f], cuB0, a0, 0, 0, 0);
                        a0 = __builtin_amdgcn_mfma_f32_16x16x32_bf16(ah[f], cuB2, a0, 0, 0, 0);
                        a0 = __builtin_amdgcn_mfma_f32_16x16x32_bf16(ah[f], cuB0, a0, 0, 0, 0);
                        acc[f][0] = a0;
                        f32x4 a1 = acc[f][1];
                        a1 = __builtin_amdgcn_mfma_f32_16x16x32_bf16(al[f], cuB1, a1, 0, 0, 0);
                        a1 = __builtin_amdgcn_mfma_f32_16x16x32_bf16(ah[f], cuB3, a1, 0, 0, 0);
                        a1 = __builtin_amdgcn_mfma_f32_16x16x32_bf16(ah[f], cuB1, a1, 0, 0, 0);
                        acc[f][1] = a1;
                    }
                    __builtin_amdgcn_s_setprio(0);
                }
            }

            const int cbase = t * 256 + wv * 32 + l15;   // + c*16
            if constexpr (MODE == 0) {
                // fold tile pair into running top-3 (values + idx for top-2)
#pragma unroll
                for (int f = 0; f < 4; ++f)
#pragma unroll
                    for (int g = 0; g < 4; ++g) {
                        float v0 = fmaf(-2.0f, acc[f][0][g], A_r[f][g]);
                        float v1 = fmaf(-2.0f, acc[f][1][g], A_r[f][g]);
                        bool sw = v1 < v0;
                        float lo = sw ? v1 : v0, hi = sw ? v0 : v1;
                        int ilo = sw ? cbase + 16 : cbase;
                        int ihi = sw ? cbase : cbase + 16;
                        bool cond = lo < r1v[f][g];
                        float A2 = cond ? hi : r2v[f][g];
                        float A3 = cond ? 3.4e38f : r3v[f][g];
                        float B1 = cond ? r1v[f][g] : lo;
                        float B2 = cond ? r2v[f][g] : hi;
                        int iA2 = cond ? ihi : c2v[f][g];
                        int iB1 = cond ? c1v[f][g] : ilo;
                        r1v[f][g] = cond ? lo : r1v[f][g];
                        c1v[f][g] = cond ? ilo : c1v[f][g];
                        bool d = B1 < A2;
                        r2v[f][g] = d ? B1 : A2;
                        c2v[f][g] = d ? iB1 : iA2;
                        r3v[f][g] = d ? fminf(A2, B2) : fminf(A3, B1);
                    }
            } else {
#pragma unroll
                for (int f = 0; f < 4; ++f)
#pragma unroll
                    for (int g = 0; g < 4; ++g) {
                        float thr = s1v[f][g] + FLAG_GAP;
#pragma unroll
                        for (int c = 0; c < 2; ++c) {
                            float v = fmaf(-2.0f, acc[f][c][g], A_r[f][g]);
                            if (v <= thr) {
                                int slot = atomicAdd(candcnt, 1);
                                if (slot < CAND_CAP)
                                    cand[slot] = ((unsigned)rid[f][g] << 13) |
                                                 (unsigned)(cbase + c * 16);
                            }
                        }
                    }
            }
        }

        if constexpr (MODE == 0) break;
        else task += gridDim.x;
    }

    if constexpr (MODE == 0) {
        __syncthreads();   // all waves done reading Xs before aliasing it as red[]
        u64* red = (u64*)Xs;   // [8 waves][64 rows][3] = 12KB
#pragma unroll
        for (int f = 0; f < 4; ++f)
#pragma unroll
            for (int g = 0; g < 4; ++g) {
                u64 k1 = ((u64)fkey(r1v[f][g]) << 32) | (unsigned)c1v[f][g];
                u64 k2 = ((u64)fkey(r2v[f][g]) << 32) | (unsigned)c2v[f][g];
                u64 k3 = ((u64)fkey(r3v[f][g]) << 32) | 0x1fffu;   // idx unused
#pragma unroll
                for (int m = 1; m < 16; m <<= 1) {
                    u64 o1 = __shfl_xor(k1, m, 64);
                    u64 o2 = __shfl_xor(k2, m, 64);
                    u64 o3 = __shfl_xor(k3, m, 64);
                    triple_merge(k1, k2, k3, o1, o2, o3);
                }
                if (l15 == 0) {
                    int row64 = f * 16 + sub * 4 + g;
                    red[(wv * 64 + row64) * 3 + 0] = k1;
                    red[(wv * 64 + row64) * 3 + 1] = k2;
                    red[(wv * 64 + row64) * 3 + 2] = k3;
                }
            }
        __syncthreads();
        if (tid < 64) {
            u64 K1 = red[tid * 3 + 0], K2 = red[tid * 3 + 1], K3 = red[tid * 3 + 2];
#pragma unroll
            for (int w = 1; w < 8; ++w) {
                triple_merge(K1, K2, K3,
                             red[(w * 64 + tid) * 3 + 0],
                             red[(w * 64 + tid) * 3 + 1],
                             red[(w * 64 + tid) * 3 + 2]);
            }
            int r = blockIdx.x * 64 + tid;
            ws_idx[r] = (int)(unsigned)(K1 & 0xffffffffull);
            float s1 = fkeyinv((unsigned)(K1 >> 32));
            float s2 = fkeyinv((unsigned)(K2 >> 32));
            float s3 = fkeyinv((unsigned)(K3 >> 32));
            s1buf[r] = s1;
            if (s2 - s1 < FLAG_GAP) {
                keybuf[r] = ~0ull;
                flaglist[atomicAdd(flagcnt, 1)] = r;
                int cs = atomicAdd(candcnt, 2);
                if (cs + 1 < CAND_CAP) {
                    cand[cs]     = ((unsigned)r << 13) | (unsigned)(K1 & 8191ull);
                    cand[cs + 1] = ((unsigned)r << 13) | (unsigned)(K2 & 8191ull);
                }
                if (s3 - s1 <= GAP3) list2[atomicAdd(cnt2, 1)] = r;
            }
        }
    }
}

// ------- Kernel C: fp64 np-semantics scoring of candidates, atomicMin merge -------
__global__ void vq_refine_cand(const float* __restrict__ X, const float* __restrict__ E,
                               const float* __restrict__ Arow, u64* __restrict__ keybuf,
                               const unsigned* __restrict__ cand,
                               const int* __restrict__ candcnt) {
    int cnt2 = *candcnt;
    cnt2 = cnt2 < CAND_CAP ? cnt2 : CAND_CAP;
    const int gw = (blockIdx.x * 256 + threadIdx.x) >> 6;   // global wave id
    const int nw = gridDim.x * 4;
    const int lane = threadIdx.x & 63;
    for (int i = gw; i < cnt2; i += nw) {
        unsigned p = cand[i];
        int row = (int)(p >> 13), code = (int)(p & 8191);
        float4 xv = *(const float4*)(X + (size_t)row * DIM + lane * 4);
        float4 ev = *(const float4*)(E + (size_t)code * DIM + lane * 4);
        double s = (double)xv.x * ev.x + (double)xv.y * ev.y +
                   (double)xv.z * ev.z + (double)xv.w * ev.w;
#pragma unroll
        for (int m = 1; m < 64; m <<= 1) s += __shfl_xor(s, m, 64);
        if (lane == 0) {
            float m32 = (float)s;
            float scr = fmaf(-2.0f, m32, Arow[row]);
            u64 key = ((u64)fkey(scr) << 32) | (unsigned)code;
            atomicMin(keybuf + row, key);
        }
    }
}

// ------- Kernel C2: apply refined winners (defensive: skip untouched sentinel) -------
__global__ void vq_apply(const u64* __restrict__ keybuf, const int* __restrict__ flaglist,
                         const int* __restrict__ flagcnt, int* __restrict__ ws_idx) {
    int s = blockIdx.x * 256 + threadIdx.x;
    if (s < *flagcnt) {
        int r = flaglist[s];
        u64 k = keybuf[r];
        if (k != ~0ull) ws_idx[r] = (int)(unsigned)(k & 0xffffffffull);
    }
}

// ---------------- Kernel D: gather quantized (ST-mimic), loss partials ----------------
__global__ void vq_out(const float* __restrict__ X, const float* __restrict__ E,
                       const int* __restrict__ ws_idx, float* __restrict__ out,
                       float* __restrict__ partials) {
    const int r = (blockIdx.x * 256 + threadIdx.x) >> 6;
    const int lane = threadIdx.x & 63;
    int idx = ws_idx[r];
    idx = idx < 0 ? 0 : (idx > N_CODES - 1 ? N_CODES - 1 : idx);   // defensive clamp
    float4 e = *((const float4*)(E + (size_t)idx * DIM + lane * 4));
    float4 x = *((const float4*)(X + (size_t)r * DIM + lane * 4));
    float dx = e.x - x.x, dy = e.y - x.y, dz = e.z - x.z, dw = e.w - x.w;
    float4 o;
    o.x = x.x + dx; o.y = x.y + dy; o.z = x.z + dz; o.w = x.w + dw;
    *((float4*)(out + (size_t)r * DIM + lane * 4)) = o;
    float s = dx * dx + dy * dy + dz * dz + dw * dw;
#pragma unroll
    for (int m = 1; m < 64; m <<= 1) s += __shfl_xor(s, m, 64);
    if (lane == 0) {
        partials[r] = s;
        out[OUT_IDX + r] = (float)idx;
    }
}

// ---------------- Kernel E: deterministic loss reduction ----------------
__global__ void vq_loss(const float* __restrict__ partials, float* __restrict__ out) {
    __shared__ double sred[4];
    double s = 0.0;
    for (int i = threadIdx.x; i < N_ROWS; i += 256) s += (double)partials[i];
#pragma unroll
    for (int m = 1; m < 64; m <<= 1) s += __shfl_xor(s, m, 64);
    if ((threadIdx.x & 63) == 0) sred[threadIdx.x >> 6] = s;
    __syncthreads();
    if (threadIdx.x == 0) {
        double t = sred[0] + sred[1] + sred[2] + sred[3];
        out[OUT_LOSS] = (float)(2.0 * t / (double)OUT_Q);
    }
}

extern "C" void kernel_launch(void* const* d_in, const int* in_sizes, int n_in,
                              void* d_out, int out_size, void* d_ws, size_t ws_size,
                              hipStream_t stream) {
    const float* X = (const float*)d_in[0];
    const float* E = (const float*)d_in[1];
    float* out = (float*)d_out;
    char* ws = (char*)d_ws;

    float* Arow = (float*)(ws + WS_AROW);
    int* idx = (int*)(ws + WS_IDX);
    int* list = (int*)(ws + WS_LIST);
    int* cnt = (int*)(ws + WS_CNT);
    int* cnt2 = (int*)(ws + WS_CNT + 8);
    int* ccnt = (int*)(ws + WS_CNT + 16);
    float* s1buf = (float*)(ws + WS_S1);
    u64* keys = (u64*)(ws + WS_KEYS);
    float* part = (float*)(ws + WS_PART);   // aliased onto keys (dead by then)
    char* eimg = (ws_size >= (size_t)(WS_EIMG + 8 * 1024 * 1024)) ? (ws + WS_EIMG) : (char*)d_out;
    unsigned* cand = (unsigned*)((char*)d_out + (16 << 20));   // [16MB,17MB) of d_out
    int* list2 = (int*)((char*)d_out + (17 << 20));            // [17MB,17.125MB) of d_out
    // both scratch regions are overwritten by vq_out afterwards

    hipMemsetAsync(ws + WS_CNT, 0, 32, stream);   // zero flagcnt + cnt2 + candcnt
    vq_prepE<<<1024, 256, 0, stream>>>(E, eimg);
    vq_rowA<<<N_ROWS / 4, 256, 0, stream>>>(X, Arow);
    vq_scan<0><<<N_ROWS / 64, 512, 0, stream>>>(X, eimg, Arow, idx, list, cnt, keys, s1buf,
                                                cand, ccnt, list2, cnt2);
    vq_scan<1><<<512, 512, 0, stream>>>(X, eimg, Arow, idx, list2, cnt2, keys, s1buf,
                                        cand, ccnt, list2, cnt2);
    vq_refine_cand<<<1024, 256, 0, stream>>>(X, E, Arow, keys, cand, ccnt);
    vq_apply<<<128, 256, 0, stream>>>(keys, list, cnt, idx);
    vq_out<<<N_ROWS / 4, 256, 0, stream>>>(X, E, idx, out, part);
    vq_loss<<<1, 256, 0, stream>>>(part, out);
}